// Round 6
// baseline (148.943 us; speedup 1.0000x reference)
//
#include <hip/hip_runtime.h>
#include <hip/hip_bf16.h>
#include <math.h>

#define SEQ 16384
#define D   1024
#define NBLK_DOT 4096        // 4 waves/block, 2 rows/wave -> 8 rows/block
#define NWAVES   16384       // total waves; 8192 per head

typedef float floatx4 __attribute__((ext_vector_type(4)));

// ---------------------------------------------------------------------------
// Kernel 1: logits + PER-WAVE softmax partials (no LDS, no __syncthreads --
// waves retire the moment their stores issue, maximizing block turnover).
// Each wave: 2 consecutive rows, 8 independent dwordx4 loads issued together.
// Blocks 0..2047 -> head 0, 2048..4095 -> head 1.
// partials[w] = (m_w, s_w) as float2, one store from lane 0.
// ---------------------------------------------------------------------------
__global__ __launch_bounds__(256) void dot_partial_kernel(
    const float* __restrict__ g1, const float* __restrict__ g2,
    const float* __restrict__ wp1, const float* __restrict__ wp2,
    float* __restrict__ logits, float2* __restrict__ partials) {
  const int lane = threadIdx.x & 63;
  const int wid  = threadIdx.x >> 6;                 // 0..3
  const int w    = blockIdx.x * 4 + wid;             // 0..16383
  const int r0   = w * 2;                            // global row pair
  const bool head1 = (blockIdx.x >= NBLK_DOT / 2);
  const float* g  = head1 ? g2 : g1;
  const float* wp = head1 ? wp2 : wp1;
  const int row0  = head1 ? (r0 - SEQ) : r0;

  floatx4 wv0 = *((const floatx4*)wp + lane);
  floatx4 wv1 = *((const floatx4*)wp + lane + 64);
  floatx4 wv2 = *((const floatx4*)wp + lane + 128);
  floatx4 wv3 = *((const floatx4*)wp + lane + 192);

  const floatx4* rv = (const floatx4*)(g + (size_t)row0 * D);
  // 8 independent 16B loads, issued back-to-back (2 rows x 4 chunks)
  floatx4 a0 = rv[lane];
  floatx4 a1 = rv[lane + 64];
  floatx4 a2 = rv[lane + 128];
  floatx4 a3 = rv[lane + 192];
  floatx4 b0 = rv[lane + 256];
  floatx4 b1 = rv[lane + 320];
  floatx4 b2 = rv[lane + 384];
  floatx4 b3 = rv[lane + 448];

  float acc0 = 0.f, acc1 = 0.f;
#pragma unroll
  for (int e = 0; e < 4; ++e) {
    acc0 = fmaf(a0[e], wv0[e], acc0);
    acc0 = fmaf(a1[e], wv1[e], acc0);
    acc0 = fmaf(a2[e], wv2[e], acc0);
    acc0 = fmaf(a3[e], wv3[e], acc0);
    acc1 = fmaf(b0[e], wv0[e], acc1);
    acc1 = fmaf(b1[e], wv1[e], acc1);
    acc1 = fmaf(b2[e], wv2[e], acc1);
    acc1 = fmaf(b3[e], wv3[e], acc1);
  }
#pragma unroll
  for (int off = 32; off > 0; off >>= 1) {
    acc0 += __shfl_xor(acc0, off, 64);
    acc1 += __shfl_xor(acc1, off, 64);
  }
  if (lane == 0) {
    *(float2*)(logits + r0) = make_float2(acc0, acc1);
    float mw = fmaxf(acc0, acc1);
    float sw = __expf(acc0 - mw) + __expf(acc1 - mw);
    partials[w] = make_float2(mw, sw);
  }
}

// ---------------------------------------------------------------------------
// Kernel 2: fused stats + normalize. 32 blocks x 256 threads.
// Blocks 0..15 -> head 0, 16..31 -> head 1. Each block redundantly reduces
// its head's 8192 (m,s) wave-partials (64 KB, L2-hot; 32 per thread), then
// normalizes its 256-float4 slice of the output.
// ---------------------------------------------------------------------------
__global__ __launch_bounds__(256) void finalize_kernel(
    const float2* __restrict__ partials,
    const float4* __restrict__ logits4, float4* __restrict__ out4) {
  const int head = blockIdx.x >> 4;          // 16 blocks per head
  const int tid  = threadIdx.x;
  const int lane = tid & 63;
  const int wid  = tid >> 6;

  // --- reduce 8192 wave-partials: 32 per thread ---
  const float2* pp = partials + head * (NWAVES / 2) + tid * 32;
  float M = -INFINITY, S = 0.f;
#pragma unroll
  for (int i = 0; i < 32; ++i) {
    float2 p = pp[i];
    float nm = fmaxf(M, p.x);
    S = S * __expf(M - nm) + p.y * __expf(p.x - nm);
    M = nm;
  }
#pragma unroll
  for (int off = 32; off > 0; off >>= 1) {
    float m2 = __shfl_xor(M, off, 64);
    float s2 = __shfl_xor(S, off, 64);
    float nm = fmaxf(M, m2);
    S = S * __expf(M - nm) + s2 * __expf(m2 - nm);
    M = nm;
  }
  __shared__ float sm[4], ss[4], fin[2];
  if (lane == 0) { sm[wid] = M; ss[wid] = S; }
  __syncthreads();
  if (tid == 0) {
    float Mg = -INFINITY, Sg = 0.f;
#pragma unroll
    for (int i = 0; i < 4; ++i) {
      float nm = fmaxf(Mg, sm[i]);
      Sg = Sg * __expf(Mg - nm) + ss[i] * __expf(sm[i] - nm);
      Mg = nm;
    }
    fin[0] = Mg;
    fin[1] = 1.0f / Sg;
  }
  __syncthreads();
  const float Mg   = fin[0];
  const float invS = fin[1];

  // --- normalize this block's slice: 256 float4 ---
  const int i = head * 4096 + (blockIdx.x & 15) * 256 + tid;
  float4 v = logits4[i];
  float4 o;
  o.x = __expf(v.x - Mg) * invS;
  o.y = __expf(v.y - Mg) * invS;
  o.z = __expf(v.z - Mg) * invS;
  o.w = __expf(v.w - Mg) * invS;
  out4[i] = o;
}

extern "C" void kernel_launch(void* const* d_in, const int* in_sizes, int n_in,
                              void* d_out, int out_size, void* d_ws, size_t ws_size,
                              hipStream_t stream) {
  const float* g1  = (const float*)d_in[0];
  const float* g2  = (const float*)d_in[1];
  const float* wp1 = (const float*)d_in[2];
  const float* wp2 = (const float*)d_in[3];
  float* out = (float*)d_out;

  float*  logits   = (float*)d_ws;                 // 32768 floats
  float2* partials = (float2*)(logits + 2 * SEQ);  // 16384 float2

  dot_partial_kernel<<<NBLK_DOT, 256, 0, stream>>>(g1, g2, wp1, wp2,
                                                   logits, partials);
  finalize_kernel<<<32, 256, 0, stream>>>(partials,
                                          (const float4*)logits, (float4*)out);
}

// Round 7
// 142.004 us; speedup vs baseline: 1.0489x; 1.0489x over previous
//
#include <hip/hip_runtime.h>
#include <hip/hip_bf16.h>
#include <math.h>

#define SEQ 16384
#define D   1024
#define NBLK_DOT 4096        // 4 waves/block, 2 rows/wave -> 8 rows/block
#define NWAVES   16384       // total waves; 8192 per head

typedef float floatx4 __attribute__((ext_vector_type(4)));

__device__ __forceinline__ floatx4 nt_load4(const floatx4* p) {
  return __builtin_nontemporal_load(p);
}

// ---------------------------------------------------------------------------
// Kernel 1: logits + PER-WAVE softmax partials (no LDS, no __syncthreads --
// waves retire the moment their stores issue). Each wave: 2 consecutive
// rows, 8 independent nontemporal dwordx4 loads issued together.
// Blocks 0..2047 -> head 0, 2048..4095 -> head 1.
// partials[w] = (m_w, s_w) as float2, one store from lane 0.
// ---------------------------------------------------------------------------
__global__ __launch_bounds__(256) void dot_partial_kernel(
    const float* __restrict__ g1, const float* __restrict__ g2,
    const float* __restrict__ wp1, const float* __restrict__ wp2,
    float* __restrict__ logits, float2* __restrict__ partials) {
  const int lane = threadIdx.x & 63;
  const int wid  = threadIdx.x >> 6;                 // 0..3
  const int w    = blockIdx.x * 4 + wid;             // 0..16383
  const int r0   = w * 2;                            // global row pair
  const bool head1 = (blockIdx.x >= NBLK_DOT / 2);
  const float* g  = head1 ? g2 : g1;
  const float* wp = head1 ? wp2 : wp1;
  const int row0  = head1 ? (r0 - SEQ) : r0;

  floatx4 wv0 = *((const floatx4*)wp + lane);
  floatx4 wv1 = *((const floatx4*)wp + lane + 64);
  floatx4 wv2 = *((const floatx4*)wp + lane + 128);
  floatx4 wv3 = *((const floatx4*)wp + lane + 192);

  const floatx4* rv = (const floatx4*)(g + (size_t)row0 * D);
  // 8 independent 16B nontemporal loads, issued back-to-back (2 rows x 4)
  floatx4 a0 = nt_load4(rv + lane);
  floatx4 a1 = nt_load4(rv + lane + 64);
  floatx4 a2 = nt_load4(rv + lane + 128);
  floatx4 a3 = nt_load4(rv + lane + 192);
  floatx4 b0 = nt_load4(rv + lane + 256);
  floatx4 b1 = nt_load4(rv + lane + 320);
  floatx4 b2 = nt_load4(rv + lane + 384);
  floatx4 b3 = nt_load4(rv + lane + 448);

  float acc0 = 0.f, acc1 = 0.f;
#pragma unroll
  for (int e = 0; e < 4; ++e) {
    acc0 = fmaf(a0[e], wv0[e], acc0);
    acc0 = fmaf(a1[e], wv1[e], acc0);
    acc0 = fmaf(a2[e], wv2[e], acc0);
    acc0 = fmaf(a3[e], wv3[e], acc0);
    acc1 = fmaf(b0[e], wv0[e], acc1);
    acc1 = fmaf(b1[e], wv1[e], acc1);
    acc1 = fmaf(b2[e], wv2[e], acc1);
    acc1 = fmaf(b3[e], wv3[e], acc1);
  }
#pragma unroll
  for (int off = 32; off > 0; off >>= 1) {
    acc0 += __shfl_xor(acc0, off, 64);
    acc1 += __shfl_xor(acc1, off, 64);
  }
  if (lane == 0) {
    *(float2*)(logits + r0) = make_float2(acc0, acc1);
    float mw = fmaxf(acc0, acc1);
    float sw = __expf(acc0 - mw) + __expf(acc1 - mw);
    partials[w] = make_float2(mw, sw);
  }
}

// ---------------------------------------------------------------------------
// Kernel 2: fused stats + normalize. 32 blocks x 256 threads.
// Blocks 0..15 -> head 0, 16..31 -> head 1. Each block redundantly reduces
// its head's 8192 (m,s) wave-partials (64 KB, L2-hot; 32 per thread), then
// normalizes its 256-float4 slice of the output.
// ---------------------------------------------------------------------------
__global__ __launch_bounds__(256) void finalize_kernel(
    const float2* __restrict__ partials,
    const float4* __restrict__ logits4, float4* __restrict__ out4) {
  const int head = blockIdx.x >> 4;          // 16 blocks per head
  const int tid  = threadIdx.x;
  const int lane = tid & 63;
  const int wid  = tid >> 6;

  // --- reduce 8192 wave-partials: 32 per thread ---
  const float2* pp = partials + head * (NWAVES / 2) + tid * 32;
  float M = -INFINITY, S = 0.f;
#pragma unroll
  for (int i = 0; i < 32; ++i) {
    float2 p = pp[i];
    float nm = fmaxf(M, p.x);
    S = S * __expf(M - nm) + p.y * __expf(p.x - nm);
    M = nm;
  }
#pragma unroll
  for (int off = 32; off > 0; off >>= 1) {
    float m2 = __shfl_xor(M, off, 64);
    float s2 = __shfl_xor(S, off, 64);
    float nm = fmaxf(M, m2);
    S = S * __expf(M - nm) + s2 * __expf(m2 - nm);
    M = nm;
  }
  __shared__ float sm[4], ss[4], fin[2];
  if (lane == 0) { sm[wid] = M; ss[wid] = S; }
  __syncthreads();
  if (tid == 0) {
    float Mg = -INFINITY, Sg = 0.f;
#pragma unroll
    for (int i = 0; i < 4; ++i) {
      float nm = fmaxf(Mg, sm[i]);
      Sg = Sg * __expf(Mg - nm) + ss[i] * __expf(sm[i] - nm);
      Mg = nm;
    }
    fin[0] = Mg;
    fin[1] = 1.0f / Sg;
  }
  __syncthreads();
  const float Mg   = fin[0];
  const float invS = fin[1];

  // --- normalize this block's slice: 256 float4 ---
  const int i = head * 4096 + (blockIdx.x & 15) * 256 + tid;
  float4 v = logits4[i];
  float4 o;
  o.x = __expf(v.x - Mg) * invS;
  o.y = __expf(v.y - Mg) * invS;
  o.z = __expf(v.z - Mg) * invS;
  o.w = __expf(v.w - Mg) * invS;
  out4[i] = o;
}

extern "C" void kernel_launch(void* const* d_in, const int* in_sizes, int n_in,
                              void* d_out, int out_size, void* d_ws, size_t ws_size,
                              hipStream_t stream) {
  const float* g1  = (const float*)d_in[0];
  const float* g2  = (const float*)d_in[1];
  const float* wp1 = (const float*)d_in[2];
  const float* wp2 = (const float*)d_in[3];
  float* out = (float*)d_out;

  float*  logits   = (float*)d_ws;                 // 32768 floats
  float2* partials = (float2*)(logits + 2 * SEQ);  // 16384 float2

  dot_partial_kernel<<<NBLK_DOT, 256, 0, stream>>>(g1, g2, wp1, wp2,
                                                   logits, partials);
  finalize_kernel<<<32, 256, 0, stream>>>(partials,
                                          (const float4*)logits, (float4*)out);
}